// Round 1
// baseline (9.779 us; speedup 1.0000x reference)
//
#include <hip/hip_runtime.h>

// SoftPattern reduces analytically to 0.0:
// band mask (j >= i) & (j < i+2) & (j < p-1) zeroes column p-1 = 6 of every
// transition matrix T_t exactly. The scan accumulates score += hidden[6], and
// hidden[6] = sum_i hidden[i]*T_t[i][6] + start[6] = 0 + 0 = 0 at every step.
// So the output is exactly 0.0f for any doc/embeddings/w. We only need to
// clear d_out (the harness poisons it with 0xAA).

__global__ void SoftPattern_zero_kernel(float* __restrict__ out, int n) {
    int i = blockIdx.x * blockDim.x + threadIdx.x;
    if (i < n) out[i] = 0.0f;
}

extern "C" void kernel_launch(void* const* d_in, const int* in_sizes, int n_in,
                              void* d_out, int out_size, void* d_ws, size_t ws_size,
                              hipStream_t stream) {
    (void)d_in; (void)in_sizes; (void)n_in; (void)d_ws; (void)ws_size;
    float* out = (float*)d_out;
    int n = out_size;            // expected: 1 (scalar score)
    int block = 64;
    int grid = (n + block - 1) / block;
    SoftPattern_zero_kernel<<<grid, block, 0, stream>>>(out, n);
}